// Round 10
// baseline (3224.347 us; speedup 1.0000x reference)
//
#include <hip/hip_runtime.h>
#include <hip/hip_bf16.h>
#include <stdint.h>

#define T_SEQ 2048
#define DDIM 256
#define G3 768
#define NB 64
#define NQR 10

typedef _Float16 h2f __attribute__((ext_vector_type(2)));
typedef _Float16 f16x8 __attribute__((ext_vector_type(8)));
typedef float f32x4 __attribute__((ext_vector_type(4)));
typedef unsigned u32x4 __attribute__((ext_vector_type(4)));

__device__ __forceinline__ float fdot2u(unsigned a, unsigned b, float c) {
    return __builtin_amdgcn_fdot2(__builtin_bit_cast(h2f, a),
                                  __builtin_bit_cast(h2f, b), c, false);
}
__device__ __forceinline__ unsigned packf16(float a, float b) {
    auto p = __builtin_amdgcn_cvt_pkrtz(a, b);   // __fp16 ext_vector(2)
    return __builtin_bit_cast(unsigned, p);
}
__device__ __forceinline__ float unpk(unsigned u, int hi) {
    h2f p = __builtin_bit_cast(h2f, u);
    return hi ? (float)p[1] : (float)p[0];
}
__device__ __forceinline__ float sigmf(float x) { return 1.0f / (1.0f + __expf(-x)); }
__device__ __forceinline__ float tanhff(float x) {
    float ax = fabsf(x);
    float e = __expf(2.0f * ax);
    float t = 1.0f - 2.0f / (e + 1.0f);
    return copysignf(t, x);
}

// ---------------- prologue: span selection + wcol + bsum ----------------
__global__ __launch_bounds__(256) void k_prologue(
    const float* __restrict__ logits, const float* __restrict__ spans,
    const float* __restrict__ W_sal, const float* __restrict__ b_sal,
    int* __restrict__ meta, float* __restrict__ wcol, float* __restrict__ bsum) {
    int tid = threadIdx.x;
    if (tid < NB) {
        int b = tid;
        float bestv = -1e30f; int best = 0;
        for (int q = 0; q < NQR; ++q) {
            float l0 = logits[(b * NQR + q) * 2 + 0];
            float l1 = logits[(b * NQR + q) * 2 + 1];
            float sc = sigmf(l0 - l1);   // monotone in softmax[...,0]
            if (sc > bestv) { bestv = sc; best = q; }
        }
        float cx = spans[(b * NQR + best) * 2 + 0];
        float w  = spans[(b * NQR + best) * 2 + 1];
        float x0 = (cx - 0.5f * w) * (float)(T_SEQ * 2);
        float x1 = (cx + 0.5f * w) * (float)(T_SEQ * 2);
        int se0 = (int)floorf(x0 * 0.5f);
        int se1 = (int)floorf(x1 * 0.5f);
        int start = min(max(se0, 0), T_SEQ - 1);
        int end_eff = min(se1, T_SEQ - 1);
        int len = end_eff - start + 1;
        if (len < 0) len = 0;
        meta[b] = start; meta[NB + b] = len;
    }
    float acc = 0.f;
    for (int e = 0; e < DDIM; ++e) acc += W_sal[e * DDIM + tid];
    wcol[tid] = acc;
    if (tid < 64) {
        float p = b_sal[tid] + b_sal[tid + 64] + b_sal[tid + 128] + b_sal[tid + 192];
        for (int off = 32; off; off >>= 1) p += __shfl_down(p, off, 64);
        if (tid == 0) *bsum = p;
    }
}

// ---------------- prep: transpose W_ih + pack W_hh to u32x4 f16 quads ----------
__global__ __launch_bounds__(256) void k_prep(
    const float* __restrict__ W_ih, const float* __restrict__ W_hh,
    float* __restrict__ wt_ih, unsigned* __restrict__ w4) {
    int g = blockIdx.x, k = threadIdx.x;
    wt_ih[k * G3 + g] = W_ih[g * DDIM + k];
    if (k < 128) {  // k = pair index
        unsigned v = packf16(W_hh[g * DDIM + 2 * k], W_hh[g * DDIM + 2 * k + 1]);
        w4[((k >> 2) * G3 + g) * 4 + (k & 3)] = v;
    }
}

// ---------------- prep2: W_hh -> MFMA B-fragments (f16 packed) ----------------
// frag f = wt*8 + kc, wt = col/16 in [0,48); lane l, jj in [0,4):
//   B[k][col]: col = wt*16 + (l&15), k = kc*32 + (l>>4)*8 + jj*2 (+1 hi half)
__global__ __launch_bounds__(256) void k_prep2(
    const float* __restrict__ W_hh, unsigned* __restrict__ wfrag) {
    int u = blockIdx.x * 256 + threadIdx.x;     // 98304 total
    int jj = u & 3;
    int l  = (u >> 2) & 63;
    int kc = (u >> 8) & 7;
    int wt = u >> 11;
    int col = wt * 16 + (l & 15);
    int k = kc * 32 + ((l >> 4) << 3) + jj * 2;
    wfrag[u] = packf16(W_hh[col * DDIM + k], W_hh[col * DDIM + k + 1]);
}

// ---------------- gi GEMM: gi[b,t,g] = sliced[b,t,:]@W_ih[g,:] + b_ih ----------------
// output packed f16 pairs: gi2[(b*TC+t)*384 + gate*128 + (col>>1)]
__global__ __launch_bounds__(256) void k_gemm(
    const float* __restrict__ src_vid, const float* __restrict__ wt_ih,
    const float* __restrict__ b_ih, const int* __restrict__ meta,
    unsigned* __restrict__ gi2, int t0, int tc, int TC) {
    int b = blockIdx.y;
    int len = meta[NB + b];
    int tb = t0 + blockIdx.x * 16;
    int tcap = t0 + tc; if (tcap > len) tcap = len;
    if (tb >= tcap) return;
    int start = meta[b];
    int j = threadIdx.x;
    int nval = tcap - tb; if (nval > 16) nval = 16;
    float aR[16], aZ[16], aN[16];
    float bR = b_ih[j], bZ = b_ih[DDIM + j], bN = b_ih[2 * DDIM + j];
#pragma unroll
    for (int r = 0; r < 16; ++r) { aR[r] = bR; aZ[r] = bZ; aN[r] = bN; }
    const float* xb = src_vid + ((size_t)b * T_SEQ + start + tb) * DDIM;
    for (int kq = 0; kq < 64; ++kq) {
        float4 xq[16];
#pragma unroll
        for (int r = 0; r < 16; ++r) {
            if (r < nval) xq[r] = *(const float4*)(xb + r * DDIM + kq * 4);
            else          xq[r] = make_float4(0.f, 0.f, 0.f, 0.f);
        }
#pragma unroll
        for (int e = 0; e < 4; ++e) {
            int k = kq * 4 + e;
            float wR = wt_ih[k * G3 + j];
            float wZ = wt_ih[k * G3 + DDIM + j];
            float wN = wt_ih[k * G3 + 2 * DDIM + j];
#pragma unroll
            for (int r = 0; r < 16; ++r) {
                float xv = (e == 0) ? xq[r].x : (e == 1) ? xq[r].y : (e == 2) ? xq[r].z : xq[r].w;
                aR[r] = fmaf(xv, wR, aR[r]);
                aZ[r] = fmaf(xv, wZ, aZ[r]);
                aN[r] = fmaf(xv, wN, aN[r]);
            }
        }
    }
    unsigned* go = gi2 + ((size_t)b * TC + (tb - t0)) * 384;
    for (int r = 0; r < nval; ++r) {
        float oR = __shfl_xor(aR[r], 1, 64);
        float oZ = __shfl_xor(aZ[r], 1, 64);
        float oN = __shfl_xor(aN[r], 1, 64);
        if (!(j & 1)) {
            unsigned* gw = go + (size_t)r * 384 + (j >> 1);
            gw[0]   = packf16(aR[r], oR);
            gw[128] = packf16(aZ[r], oZ);
            gw[256] = packf16(aN[r], oN);
        }
    }
}

// ---------------- GRU recurrence: dual-pipe (MFMA r,z + fdot2 n) ----------------
// 768 threads = 12 waves, one block per batch.
// Waves 0-7 (MFMA pipe): gate g=w>>2 (0=r,1=z), tiles (w&3)*4..+4 of 16 cols.
//   A = h replicated across all 16 rows (uniform LDS reads) -> every lane's
//   D reg0 is the dot for its col. B-frags (32 quads) live in AGPRs (free).
// Waves 8-11 (VALU pipe): thread c = tid-512 computes n-gate full-K fdot2,
//   then finalizes col c (sigmoid/tanh/h-update) after barrier.
__global__ void __launch_bounds__(768) k_gru(
    const unsigned* __restrict__ gi2, const unsigned* __restrict__ w4,
    const unsigned* __restrict__ wfrag,
    const float* __restrict__ b_ih, const float* __restrict__ b_hh,
    const int* __restrict__ meta, float* __restrict__ h_state,
    int t0, int t1, int TC) {
    int b = blockIdx.x, tid = threadIdx.x;
    int lane = tid & 63, w = tid >> 6;
    int len = meta[NB + b];

    __shared__ unsigned hl[128];   // packed f16 h (256 values)
    __shared__ float rz[512];      // r,z dots from MFMA waves

    const f32x4 zf = {0.f, 0.f, 0.f, 0.f};

    if (w < 8) {
        // ---- MFMA pipe ----
        int g = w >> 2;       // 0 = r, 1 = z
        int tq = w & 3;       // tile quad within gate
        u32x4 bf[32];
        const u32x4* wfr = (const u32x4*)wfrag;
#pragma unroll
        for (int t4 = 0; t4 < 4; ++t4)
#pragma unroll
            for (int kc = 0; kc < 8; ++kc) {
                int wt = g * 16 + tq * 4 + t4;
                bf[t4 * 8 + kc] = wfr[(size_t)(wt * 8 + kc) * 64 + lane];
            }
        __syncthreads();   // initial h ready
        for (int t = t0; t < t1; ++t) {
            f32x4 cf[4];
            const u32x4* hb = (const u32x4*)hl;
#pragma unroll
            for (int kc = 0; kc < 8; ++kc) {
                u32x4 av = hb[kc * 4 + (lane >> 4)];
                f16x8 af = __builtin_bit_cast(f16x8, av);
#pragma unroll
                for (int t4 = 0; t4 < 4; ++t4) {
                    cf[t4] = __builtin_amdgcn_mfma_f32_16x16x32_f16(
                        af, __builtin_bit_cast(f16x8, bf[t4 * 8 + kc]),
                        (kc == 0) ? zf : cf[t4], 0, 0, 0);
                }
            }
            if (lane < 16) {
#pragma unroll
                for (int t4 = 0; t4 < 4; ++t4)
                    rz[g * 256 + (tq * 4 + t4) * 16 + lane] = cf[t4][0];
            }
            __syncthreads();   // B: rz + n-dot ready
            __syncthreads();   // C: h updated
        }
    } else {
        // ---- VALU pipe + finalize ----
        int c = tid - 512;     // col in [0,256)
        u32x4 nq[32];
        const u32x4* w4v = (const u32x4*)w4;
#pragma unroll
        for (int q = 0; q < 32; ++q) nq[q] = w4v[(size_t)q * G3 + 512 + c];

        float bhR = b_hh[c], bhZ = b_hh[256 + c], bhN = b_hh[512 + c];
        float biR = b_ih[c], biZ = b_ih[256 + c], biN = b_ih[512 + c];

        float h = 0.f;
        if (t0 != 0) h = h_state[b * DDIM + c];
        {
            float hp = __shfl_xor(h, 1, 64);
            if (!(c & 1)) hl[c >> 1] = packf16(h, hp);
        }
        const unsigned* gb2 = gi2 + (size_t)b * TC * 384 + (c >> 1);
        int sel = c & 1;
        float gR = biR, gZ = biZ, gN = biN;
        if (t0 < t1 && t0 < len) {
            gR = unpk(gb2[0], sel); gZ = unpk(gb2[128], sel); gN = unpk(gb2[256], sel);
        }
        __syncthreads();   // initial h ready

        for (int t = t0; t < t1; ++t) {
            // prefetch next-step gi (hides under the dot chain)
            float nR = biR, nZ = biZ, nN = biN;
            int tn = t + 1;
            if (tn < t1 && tn < len) {
                const unsigned* gp = gb2 + (size_t)(tn - t0) * 384;
                nR = unpk(gp[0], sel); nZ = unpk(gp[128], sel); nN = unpk(gp[256], sel);
            }
            // n-gate: 128 fdot2 over packed h (uniform LDS reads)
            float a0 = 0.f, a1 = 0.f, a2 = 0.f, a3 = 0.f;
            const u32x4* hb = (const u32x4*)hl;
#pragma unroll
            for (int q = 0; q < 32; ++q) {
                u32x4 h4 = hb[q];
                a0 = fdot2u(h4.x, nq[q].x, a0);
                a1 = fdot2u(h4.y, nq[q].y, a1);
                a2 = fdot2u(h4.z, nq[q].z, a2);
                a3 = fdot2u(h4.w, nq[q].w, a3);
            }
            float hn = bhN + (a0 + a1) + (a2 + a3);
            __syncthreads();   // B: rz ready
            float hr = rz[c] + bhR;
            float hz = rz[256 + c] + bhZ;
            float r = sigmf(gR + hr);
            float z = sigmf(gZ + hz);
            float n = tanhff(gN + r * hn);
            h = (1.0f - z) * n + z * h;
            float hp = __shfl_xor(h, 1, 64);
            if (!(c & 1)) hl[c >> 1] = packf16(h, hp);
            gR = nR; gZ = nZ; gN = nN;
            __syncthreads();   // C: h updated
        }
        h_state[b * DDIM + c] = h;
    }
}

// ---------------- epilogue: saliency = ((1+h·src)·(mem·wcol)+bsum)/16 ----------------
__global__ __launch_bounds__(256) void k_epi(
    const float* __restrict__ memory, const float* __restrict__ src_vid,
    const float* __restrict__ h_state, const float* __restrict__ wcol,
    const float* __restrict__ bsum, float* __restrict__ out) {
    int wid = blockIdx.x * 4 + (threadIdx.x >> 6);
    int lane = threadIdx.x & 63;
    int b = wid >> 11;
    int t = wid & 2047;
    const float4* mp = (const float4*)(memory + ((size_t)b * T_SEQ + t) * DDIM);
    const float4* sp = (const float4*)(src_vid + ((size_t)b * T_SEQ + t) * DDIM);
    const float4* hp = (const float4*)(h_state + b * DDIM);
    const float4* wp = (const float4*)wcol;
    float4 m = mp[lane], s = sp[lane], hv = hp[lane], wc = wp[lane];
    float s1 = m.x * wc.x + m.y * wc.y + m.z * wc.z + m.w * wc.w;
    float s2 = hv.x * s.x + hv.y * s.y + hv.z * s.z + hv.w * s.w;
    for (int off = 32; off; off >>= 1) {
        s1 += __shfl_down(s1, off, 64);
        s2 += __shfl_down(s2, off, 64);
    }
    if (lane == 0) out[(size_t)b * T_SEQ + t] = ((1.0f + s2) * s1 + *bsum) * 0.0625f;
}

extern "C" void kernel_launch(void* const* d_in, const int* in_sizes, int n_in,
                              void* d_out, int out_size, void* d_ws, size_t ws_size,
                              hipStream_t stream) {
    const float* logits  = (const float*)d_in[0];
    const float* spans   = (const float*)d_in[1];
    const float* memory  = (const float*)d_in[2];
    const float* src_vid = (const float*)d_in[3];
    const float* W_ih    = (const float*)d_in[4];
    const float* W_hh    = (const float*)d_in[5];
    const float* b_ih    = (const float*)d_in[6];
    const float* b_hh    = (const float*)d_in[7];
    const float* W_sal   = (const float*)d_in[8];
    const float* b_sal   = (const float*)d_in[9];
    float* out = (float*)d_out;
    char* ws = (char*)d_ws;

    const size_t OFF_META = 0;        // 128 ints
    const size_t OFF_WCOL = 1024;     // 256 f32
    const size_t OFF_BSUM = 2048;     // 1 f32
    const size_t OFF_H    = 4096;     // 64*256 f32 = 65536
    const size_t OFF_W4   = 69632;    // 98304 u32 = 393216
    const size_t OFF_FRAG = 462848;   // 98304 u32 = 393216
    const size_t OFF_WTIH = 856064;   // 256*768 f32 = 786432
    const size_t OFF_GI   = 1642496;  // gi2 packed f16 pairs

    int* meta       = (int*)(ws + OFF_META);
    float* wcol     = (float*)(ws + OFF_WCOL);
    float* bsum     = (float*)(ws + OFF_BSUM);
    float* h_state  = (float*)(ws + OFF_H);
    unsigned* w4    = (unsigned*)(ws + OFF_W4);
    unsigned* wfrag = (unsigned*)(ws + OFF_FRAG);
    float* wt_ih    = (float*)(ws + OFF_WTIH);
    unsigned* gi2   = (unsigned*)(ws + OFF_GI);

    size_t gi_cap = (ws_size > OFF_GI) ? (ws_size - OFF_GI) : 0;
    long long tc_max = (long long)(gi_cap / ((size_t)NB * 384 * 4));
    int TC = (tc_max > T_SEQ) ? T_SEQ : (int)tc_max;
    if (TC < 16) TC = 16;

    k_prologue<<<dim3(1), dim3(256), 0, stream>>>(logits, spans, W_sal, b_sal, meta, wcol, bsum);
    k_prep<<<dim3(G3), dim3(256), 0, stream>>>(W_ih, W_hh, wt_ih, w4);
    k_prep2<<<dim3(384), dim3(256), 0, stream>>>(W_hh, wfrag);
    for (int t0 = 0; t0 < T_SEQ; t0 += TC) {
        int tc = T_SEQ - t0; if (tc > TC) tc = TC;
        k_gemm<<<dim3((tc + 15) / 16, NB), dim3(256), 0, stream>>>(
            src_vid, wt_ih, b_ih, meta, gi2, t0, tc, TC);
        k_gru<<<dim3(NB), dim3(768), 0, stream>>>(
            gi2, w4, wfrag, b_ih, b_hh, meta, h_state, t0, t0 + tc, TC);
    }
    k_epi<<<dim3(NB * T_SEQ / 4), dim3(256), 0, stream>>>(
        memory, src_vid, h_state, wcol, bsum, out);
}